// Round 5
// baseline (172.242 us; speedup 1.0000x reference)
//
#include <hip/hip_runtime.h>

#define LL 16
#define CC 32
#define HIDN 16
#define HH 64
#define WW 64
#define HW 4096   // 64*64
#define NCHUNK 51 // (t, k-chunk-of-3) pairs

// ws layout (floats):
#define CUM_OFF  0                                  // L*2*HW    = 131072
#define U_OFF    (LL * 2 * HW)                      // L*HIDN*HW = 1048576
#define V_OFF    (U_OFF + LL * HIDN * HW)           // L*HIDN*HW = 1048576
#define A_OFF    (V_OFF + LL * HIDN * HW)           // 51*CC*HW  = 6684672
// total = 8,912,896 floats (~34 MB)

// chunk tables (chunks of 3 k's per t; nch(t)=ceil((t+1)/3))
__device__ const int T_OF[NCHUNK] = {
    0, 1, 2, 3,3, 4,4, 5,5, 6,6,6, 7,7,7, 8,8,8,
    9,9,9,9, 10,10,10,10, 11,11,11,11,
    12,12,12,12,12, 13,13,13,13,13, 14,14,14,14,14,
    15,15,15,15,15,15 };
__device__ const int KC_OF[NCHUNK] = {
    0, 0, 0, 0,1, 0,1, 0,1, 0,1,2, 0,1,2, 0,1,2,
    0,1,2,3, 0,1,2,3, 0,1,2,3,
    0,1,2,3,4, 0,1,2,3,4, 0,1,2,3,4,
    0,1,2,3,4,5 };
__device__ const int CBASE[LL] = {0,1,2,3,5,7,9,12,15,18,22,26,30,35,40,45};
__device__ const int NCH[LL]   = {1,1,1,2,2,2,3,3,3,4,4,4,5,5,5,6};

// ---------------- cumsum of flows over L ----------------
__global__ __launch_bounds__(256) void cumsum_kernel(const float* __restrict__ flows,
                                                     float* __restrict__ cum) {
    int idx = blockIdx.x * 256 + threadIdx.x;   // p*HW + pix
    float acc = 0.0f;
#pragma unroll
    for (int l = 0; l < LL; ++l) {
        acc += flows[l * 2 * HW + idx];
        cum[l * 2 * HW + idx] = acc;
    }
}

// ---------------- prep: U/V halves, channel-FIRST ----------------
// U[l][o][px] = sum_c w1[o][c]    * img[l][c][px]
// V[l][o][px] = sum_c w1[o][32+c] * img[l][c][px] + b1[o]
__global__ __launch_bounds__(256) void prep_kernel(const float* __restrict__ images,
                                                   const float* __restrict__ w1,
                                                   const float* __restrict__ b1,
                                                   float* __restrict__ ws) {
    __shared__ float w1s[HIDN * 2 * CC];  // 1024 floats
    const int tid = threadIdx.x;
    ((float4*)w1s)[tid] = ((const float4*)w1)[tid];
    __syncthreads();

    const int l  = blockIdx.y;
    const int px = blockIdx.x * 256 + tid;
    const float* img = images + (size_t)l * CC * HW;

    float u[HIDN], v[HIDN];
#pragma unroll
    for (int o = 0; o < HIDN; ++o) { u[o] = 0.0f; v[o] = b1[o]; }

#pragma unroll
    for (int c = 0; c < CC; ++c) {
        float x = img[c * HW + px];   // coalesced
#pragma unroll
        for (int o = 0; o < HIDN; ++o) {
            u[o] = fmaf(w1s[o * 64 + c],      x, u[o]);
            v[o] = fmaf(w1s[o * 64 + CC + c], x, v[o]);
        }
    }

    float* Up = ws + U_OFF + (size_t)l * HIDN * HW + px;
    float* Vp = ws + V_OFF + (size_t)l * HIDN * HW + px;
#pragma unroll
    for (int o = 0; o < HIDN; ++o) {
        Up[o * HW] = u[o];    // coalesced
        Vp[o * HW] = v[o];
    }
}

// ---------------- phase A: balanced sample over (t, k-chunk of 3) ----------------
// grid: (16 px-tiles, 51 chunks), block 256 threads = 256 px, all 32 channels
__global__ __launch_bounds__(256) void sample_kernel(const float* __restrict__ images,
                                                     const float* __restrict__ ws_in,
                                                     float* __restrict__ ws_out,
                                                     const float* __restrict__ w2,
                                                     const float* __restrict__ b2,
                                                     const float* __restrict__ decay_log) {
    __shared__ float w2s[2 * HIDN];
    __shared__ float b2s2[2];
    const int tid = threadIdx.x;
    if (tid < 2 * HIDN) w2s[tid] = w2[tid];
    if (tid < 2)        b2s2[tid] = b2[tid];
    __syncthreads();

    const int cid = blockIdx.y;
    const int t   = T_OF[cid];
    const int k0  = KC_OF[cid] * 3;
    const int px  = blockIdx.x * 256 + tid;
    const int lpx = px & 63;           // x coord
    const int row = px >> 6;           // y coord

    const float* cum = ws_in + CUM_OFF;
    const float* Ub  = ws_in + U_OFF;
    const float* Vb  = ws_in + V_OFF;

    float ut[HIDN];
    {
        const float* up = Ub + (size_t)t * HIDN * HW + px;
#pragma unroll
        for (int o = 0; o < HIDN; ++o) ut[o] = up[o * HW];  // coalesced
    }

    const float cumtx = cum[(t * 2)     * HW + px];
    const float cumty = cum[(t * 2 + 1) * HW + px];
    const float lam   = expf(decay_log[0]);
    const float bgx   = (float)(2 * lpx + 1) * (1.0f / 64.0f) - 1.0f;
    const float bgy   = (float)(2 * row + 1) * (1.0f / 64.0f) - 1.0f;

    float acc[CC];
#pragma unroll
    for (int c = 0; c < CC; ++c) acc[c] = 0.0f;

#pragma unroll
    for (int dk = 0; dk < 3; ++dk) {
        const int k = k0 + dk;
        if (k <= t) {   // uniform across block
            // tiny MLP: res = W2 * relu(U[t] + V[k]) + b2
            float res0 = b2s2[0], res1 = b2s2[1];
            {
                const float* vp = Vb + (size_t)k * HIDN * HW + px;
#pragma unroll
                for (int o = 0; o < HIDN; ++o) {
                    float h = fmaxf(ut[o] + vp[o * HW], 0.0f);  // coalesced
                    res0 = fmaf(w2s[o],        h, res0);
                    res1 = fmaf(w2s[HIDN + o], h, res1);
                }
            }

            float gx = bgx + cumtx - cum[(k * 2)     * HW + px] + res0;
            float gy = bgy + cumty - cum[(k * 2 + 1) * HW + px] + res1;

            // wrap x: mod(gx+1, 2) - 1  (floor-mod)
            float xp = gx + 1.0f;
            xp = xp - floorf(xp * 0.5f) * 2.0f;
            float gxw = xp - 1.0f;

            float ix = ((gxw + 1.0f) * 64.0f - 1.0f) * 0.5f;
            float iy = ((gy  + 1.0f) * 64.0f - 1.0f) * 0.5f;

            float ix0f = floorf(ix), iy0f = floorf(iy);
            float fx1 = ix - ix0f, fy1 = iy - iy0f;
            float fx0 = 1.0f - fx1, fy0 = 1.0f - fy1;
            int ix0 = (int)ix0f, iy0 = (int)iy0f;
            int ix1 = ix0 + 1,   iy1 = iy0 + 1;

            const float wt = expf(-lam * (float)(t - k));

            int   off[4];
            float cwt[4];
            {
                int xi[4] = {ix0, ix1, ix0, ix1};
                int yi[4] = {iy0, iy0, iy1, iy1};
                float wwv[4] = {fx0 * fy0, fx1 * fy0, fx0 * fy1, fx1 * fy1};
#pragma unroll
                for (int j = 0; j < 4; ++j) {
                    bool valid = (xi[j] >= 0) & (xi[j] < WW) & (yi[j] >= 0) & (yi[j] < HH);
                    int xc = min(max(xi[j], 0), WW - 1);
                    int yc = min(max(yi[j], 0), HH - 1);
                    off[j] = yc * WW + xc;
                    cwt[j] = valid ? wwv[j] * wt : 0.0f;
                }
            }

            // channel-first gather: lanes (adjacent px) read adjacent addrs
            const float* kbase = images + (size_t)k * CC * HW;
            const float w0 = cwt[0], w1v = cwt[1], w2v = cwt[2], w3v = cwt[3];
#pragma unroll
            for (int c = 0; c < CC; ++c) {
                const float* pl = kbase + c * HW;
                float s = w0 * pl[off[0]] + w1v * pl[off[1]]
                        + w2v * pl[off[2]] + w3v * pl[off[3]];
                acc[c] += s;
            }
        }
    }

    // store partial slice A[cid][c][px] (coalesced)
    float* Ap = ws_out + A_OFF + (size_t)cid * CC * HW + px;
#pragma unroll
    for (int c = 0; c < CC; ++c) Ap[c * HW] = acc[c];
}

// ---------------- phase B: reduce over k-chunks (pure streaming) ----------------
// 2048 blocks x 256 threads; one float4 of output per thread
__global__ __launch_bounds__(256) void reduce_kernel(const float* __restrict__ ws,
                                                     float* __restrict__ out) {
    const int gid = blockIdx.x * 256 + threadIdx.x;  // 0..524287
    const int t   = gid >> 15;                        // 32*1024 float4 per t
    const int c   = (gid >> 10) & 31;
    const int px4 = gid & 1023;

    const float4* A4 = (const float4*)(ws + A_OFF);
    const int base = CBASE[t];
    const int n    = NCH[t];

    float4 s = make_float4(0.0f, 0.0f, 0.0f, 0.0f);
    for (int kc = 0; kc < n; ++kc) {
        float4 a = A4[((size_t)(base + kc) * CC + c) * (HW / 4) + px4];
        s.x += a.x; s.y += a.y; s.z += a.z; s.w += a.w;
    }
    ((float4*)out)[gid] = s;
}

extern "C" void kernel_launch(void* const* d_in, const int* in_sizes, int n_in,
                              void* d_out, int out_size, void* d_ws, size_t ws_size,
                              hipStream_t stream) {
    const float* flows     = (const float*)d_in[0];
    const float* images    = (const float*)d_in[1];
    const float* decay_log = (const float*)d_in[2];
    const float* w1        = (const float*)d_in[3];
    const float* b1        = (const float*)d_in[4];
    const float* w2        = (const float*)d_in[5];
    const float* b2        = (const float*)d_in[6];
    float* out = (float*)d_out;
    float* ws  = (float*)d_ws;

    cumsum_kernel<<<dim3(2 * HW / 256), dim3(256), 0, stream>>>(flows, ws + CUM_OFF);

    prep_kernel<<<dim3(HW / 256, LL), dim3(256), 0, stream>>>(images, w1, b1, ws);

    sample_kernel<<<dim3(HW / 256, NCHUNK), dim3(256), 0, stream>>>(
        images, ws, ws, w2, b2, decay_log);

    reduce_kernel<<<dim3(2048), dim3(256), 0, stream>>>(ws, out);
}

// Round 6
// 169.298 us; speedup vs baseline: 1.0174x; 1.0174x over previous
//
#include <hip/hip_runtime.h>

#define LL 16
#define CC 32
#define HIDN 16
#define HH 64
#define WW 64
#define HW 4096    // 64*64
#define NPAIR 136  // (t,k) with k<=t
#define NCHUNK 40  // (t, k-chunk-of-4) pairs

// ws layout (floats):
#define CUM_OFF  0                                   // 131072
#define U_OFF    (LL * 2 * HW)                       // 1048576
#define V_OFF    (U_OFF + LL * HIDN * HW)            // 1048576
#define DISP_OFF (V_OFF + LL * HIDN * HW)            // NPAIR*HW*2 = 1114112
#define A_OFF    (DISP_OFF + NPAIR * HW * 2)         // 40*CC*HW  = 5242880
// total = 8,585,216 floats (~32.7 MB)

// pair tables
__device__ const int T_PAIR[NPAIR] = {
    0, 1,1, 2,2,2, 3,3,3,3, 4,4,4,4,4, 5,5,5,5,5,5,
    6,6,6,6,6,6,6, 7,7,7,7,7,7,7,7,
    8,8,8,8,8,8,8,8,8, 9,9,9,9,9,9,9,9,9,9,
    10,10,10,10,10,10,10,10,10,10,10,
    11,11,11,11,11,11,11,11,11,11,11,11,
    12,12,12,12,12,12,12,12,12,12,12,12,12,
    13,13,13,13,13,13,13,13,13,13,13,13,13,13,
    14,14,14,14,14,14,14,14,14,14,14,14,14,14,14,
    15,15,15,15,15,15,15,15,15,15,15,15,15,15,15,15 };
__device__ const int K_PAIR[NPAIR] = {
    0, 0,1, 0,1,2, 0,1,2,3, 0,1,2,3,4, 0,1,2,3,4,5,
    0,1,2,3,4,5,6, 0,1,2,3,4,5,6,7,
    0,1,2,3,4,5,6,7,8, 0,1,2,3,4,5,6,7,8,9,
    0,1,2,3,4,5,6,7,8,9,10,
    0,1,2,3,4,5,6,7,8,9,10,11,
    0,1,2,3,4,5,6,7,8,9,10,11,12,
    0,1,2,3,4,5,6,7,8,9,10,11,12,13,
    0,1,2,3,4,5,6,7,8,9,10,11,12,13,14,
    0,1,2,3,4,5,6,7,8,9,10,11,12,13,14,15 };
__device__ const int TRI[LL] = {0,1,3,6,10,15,21,28,36,45,55,66,78,91,105,120};

// chunk-of-4 tables
__device__ const int T_OF[NCHUNK] = {
    0,1,2,3, 4,4, 5,5, 6,6, 7,7, 8,8,8, 9,9,9, 10,10,10, 11,11,11,
    12,12,12,12, 13,13,13,13, 14,14,14,14, 15,15,15,15 };
__device__ const int KC_OF[NCHUNK] = {
    0,0,0,0, 0,1, 0,1, 0,1, 0,1, 0,1,2, 0,1,2, 0,1,2, 0,1,2,
    0,1,2,3, 0,1,2,3, 0,1,2,3, 0,1,2,3 };
__device__ const int CBASE[LL] = {0,1,2,3,4,6,8,10,12,15,18,21,24,28,32,36};
__device__ const int NCH[LL]   = {1,1,1,1,2,2,2,2,3,3,3,3,4,4,4,4};

// ---------------- cumsum of flows over L ----------------
__global__ __launch_bounds__(256) void cumsum_kernel(const float* __restrict__ flows,
                                                     float* __restrict__ cum) {
    int idx = blockIdx.x * 256 + threadIdx.x;   // p*HW + pix
    float acc = 0.0f;
#pragma unroll
    for (int l = 0; l < LL; ++l) {
        acc += flows[l * 2 * HW + idx];
        cum[l * 2 * HW + idx] = acc;
    }
}

// ---------------- prep: U/V halves, channel-first ----------------
__global__ __launch_bounds__(256) void prep_kernel(const float* __restrict__ images,
                                                   const float* __restrict__ w1,
                                                   const float* __restrict__ b1,
                                                   float* __restrict__ ws) {
    __shared__ float w1s[HIDN * 2 * CC];
    const int tid = threadIdx.x;
    ((float4*)w1s)[tid] = ((const float4*)w1)[tid];
    __syncthreads();

    const int l  = blockIdx.y;
    const int px = blockIdx.x * 256 + tid;
    const float* img = images + (size_t)l * CC * HW;

    float u[HIDN], v[HIDN];
#pragma unroll
    for (int o = 0; o < HIDN; ++o) { u[o] = 0.0f; v[o] = b1[o]; }

#pragma unroll
    for (int c = 0; c < CC; ++c) {
        float x = img[c * HW + px];   // coalesced
#pragma unroll
        for (int o = 0; o < HIDN; ++o) {
            u[o] = fmaf(w1s[o * 64 + c],      x, u[o]);
            v[o] = fmaf(w1s[o * 64 + CC + c], x, v[o]);
        }
    }

    float* Up = ws + U_OFF + (size_t)l * HIDN * HW + px;
    float* Vp = ws + V_OFF + (size_t)l * HIDN * HW + px;
#pragma unroll
    for (int o = 0; o < HIDN; ++o) {
        Up[o * HW] = u[o];
        Vp[o * HW] = v[o];
    }
}

// ---------------- disp: per (t,k) pair, displacement = (cum_t - cum_k) + res ----
// grid: (16 px-tiles, 136 pairs), block 256
__global__ __launch_bounds__(256) void disp_kernel(float* __restrict__ ws,
                                                   const float* __restrict__ w2,
                                                   const float* __restrict__ b2) {
    __shared__ float w2s[2 * HIDN];
    __shared__ float b2s2[2];
    const int tid = threadIdx.x;
    if (tid < 2 * HIDN) w2s[tid] = w2[tid];
    if (tid < 2)        b2s2[tid] = b2[tid];
    __syncthreads();

    const int pair = blockIdx.y;
    const int t = T_PAIR[pair];
    const int k = K_PAIR[pair];
    const int px = blockIdx.x * 256 + tid;

    const float* cum = ws + CUM_OFF;
    const float* up  = ws + U_OFF + (size_t)t * HIDN * HW + px;
    const float* vp  = ws + V_OFF + (size_t)k * HIDN * HW + px;

    float res0 = b2s2[0], res1 = b2s2[1];
#pragma unroll
    for (int o = 0; o < HIDN; ++o) {
        float h = fmaxf(up[o * HW] + vp[o * HW], 0.0f);  // coalesced
        res0 = fmaf(w2s[o],        h, res0);
        res1 = fmaf(w2s[HIDN + o], h, res1);
    }

    // ref order: rel = cum_t - cum_k; rel += res
    float dx = (cum[(t * 2)     * HW + px] - cum[(k * 2)     * HW + px]) + res0;
    float dy = (cum[(t * 2 + 1) * HW + px] - cum[(k * 2 + 1) * HW + px]) + res1;

    ((float2*)(ws + DISP_OFF))[(size_t)pair * HW + px] = make_float2(dx, dy);
}

// ---------------- phase A: sample over (t, k-chunk of 4) ----------------
// grid: (64 row-strips, 40 chunks); block 256 = 64 px x 4 channel-groups of 8
__global__ __launch_bounds__(256) void sample_kernel(const float* __restrict__ images,
                                                     const float* __restrict__ ws_in,
                                                     float* __restrict__ ws_out,
                                                     const float* __restrict__ decay_log) {
    const int tid   = threadIdx.x;
    const int cid   = blockIdx.y;
    const int t     = T_OF[cid];
    const int k0    = KC_OF[cid] * 4;
    const int strip = blockIdx.x;      // image row
    const int lane  = tid & 63;        // x coord
    const int cg    = tid >> 6;        // channel group (one per wave)
    const int c0    = cg * 8;
    const int px    = strip * 64 + lane;

    const float2* disp2 = (const float2*)(ws_in + DISP_OFF);
    const float lam = expf(decay_log[0]);
    const float bgx = (float)(2 * lane  + 1) * (1.0f / 64.0f) - 1.0f;
    const float bgy = (float)(2 * strip + 1) * (1.0f / 64.0f) - 1.0f;

    float acc[8];
#pragma unroll
    for (int j = 0; j < 8; ++j) acc[j] = 0.0f;

#pragma unroll
    for (int dk = 0; dk < 4; ++dk) {
        const int k = k0 + dk;
        if (k > t) break;   // uniform across block; k increasing

        float2 d = disp2[(size_t)(TRI[t] + k) * HW + px];
        float gx = bgx + d.x;
        float gy = bgy + d.y;

        // wrap x: mod(gx+1, 2) - 1  (floor-mod)
        float xp = gx + 1.0f;
        xp = xp - floorf(xp * 0.5f) * 2.0f;
        float gxw = xp - 1.0f;

        float ix = ((gxw + 1.0f) * 64.0f - 1.0f) * 0.5f;
        float iy = ((gy  + 1.0f) * 64.0f - 1.0f) * 0.5f;

        float ix0f = floorf(ix), iy0f = floorf(iy);
        float fx1 = ix - ix0f, fy1 = iy - iy0f;
        float fx0 = 1.0f - fx1, fy0 = 1.0f - fy1;
        int ix0 = (int)ix0f, iy0 = (int)iy0f;
        int ix1 = ix0 + 1,   iy1 = iy0 + 1;

        const float wt = expf(-lam * (float)(t - k));

        int   off[4];
        float cwt[4];
        {
            int xi[4] = {ix0, ix1, ix0, ix1};
            int yi[4] = {iy0, iy0, iy1, iy1};
            float wwv[4] = {fx0 * fy0, fx1 * fy0, fx0 * fy1, fx1 * fy1};
#pragma unroll
            for (int j = 0; j < 4; ++j) {
                bool valid = (xi[j] >= 0) & (xi[j] < WW) & (yi[j] >= 0) & (yi[j] < HH);
                int xc = min(max(xi[j], 0), WW - 1);
                int yc = min(max(yi[j], 0), HH - 1);
                off[j] = yc * WW + xc;
                cwt[j] = valid ? wwv[j] * wt : 0.0f;
            }
        }

        const float w0 = cwt[0], w1v = cwt[1], w2v = cwt[2], w3v = cwt[3];
        const float* kbase = images + ((size_t)k * CC + c0) * HW;
#pragma unroll
        for (int j = 0; j < 8; ++j) {
            const float* pl = kbase + j * HW;
            float s = w0 * pl[off[0]] + w1v * pl[off[1]]
                    + w2v * pl[off[2]] + w3v * pl[off[3]];
            acc[j] += s;
        }
    }

    // store partial slice A[cid][c0+j][px] (coalesced per wave)
    float* Ap = ws_out + A_OFF + ((size_t)cid * CC + c0) * HW + px;
#pragma unroll
    for (int j = 0; j < 8; ++j) Ap[j * HW] = acc[j];
}

// ---------------- phase B: reduce over k-chunks (pure streaming) ----------------
__global__ __launch_bounds__(256) void reduce_kernel(const float* __restrict__ ws,
                                                     float* __restrict__ out) {
    const int gid = blockIdx.x * 256 + threadIdx.x;  // 0..524287
    const int t   = gid >> 15;                        // 32768 float4 per t
    const int c   = (gid >> 10) & 31;
    const int px4 = gid & 1023;

    const float4* A4 = (const float4*)(ws + A_OFF);
    const int base = CBASE[t];
    const int n    = NCH[t];

    float4 s = make_float4(0.0f, 0.0f, 0.0f, 0.0f);
    for (int kc = 0; kc < n; ++kc) {
        float4 a = A4[((size_t)(base + kc) * CC + c) * (HW / 4) + px4];
        s.x += a.x; s.y += a.y; s.z += a.z; s.w += a.w;
    }
    ((float4*)out)[gid] = s;
}

extern "C" void kernel_launch(void* const* d_in, const int* in_sizes, int n_in,
                              void* d_out, int out_size, void* d_ws, size_t ws_size,
                              hipStream_t stream) {
    const float* flows     = (const float*)d_in[0];
    const float* images    = (const float*)d_in[1];
    const float* decay_log = (const float*)d_in[2];
    const float* w1        = (const float*)d_in[3];
    const float* b1        = (const float*)d_in[4];
    const float* w2        = (const float*)d_in[5];
    const float* b2        = (const float*)d_in[6];
    float* out = (float*)d_out;
    float* ws  = (float*)d_ws;

    cumsum_kernel<<<dim3(2 * HW / 256), dim3(256), 0, stream>>>(flows, ws + CUM_OFF);

    prep_kernel<<<dim3(HW / 256, LL), dim3(256), 0, stream>>>(images, w1, b1, ws);

    disp_kernel<<<dim3(HW / 256, NPAIR), dim3(256), 0, stream>>>(ws, w2, b2);

    sample_kernel<<<dim3(64, NCHUNK), dim3(256), 0, stream>>>(
        images, ws, ws, decay_log);

    reduce_kernel<<<dim3(2048), dim3(256), 0, stream>>>(ws, out);
}

// Round 7
// 161.903 us; speedup vs baseline: 1.0639x; 1.0457x over previous
//
#include <hip/hip_runtime.h>

#define LL 16
#define CC 32
#define HIDN 16
#define HH 64
#define WW 64
#define HW 4096    // 64*64
#define NPAIR 136  // (t,k) with k<=t
#define NCHUNK 40  // (t, k-chunk-of-4) pairs

// ws layout (floats):
#define CUM_OFF  0                                   // 131072
#define U_OFF    (LL * 2 * HW)                       // 1048576
#define V_OFF    (U_OFF + LL * HIDN * HW)            // 1048576
#define DISP_OFF (V_OFF + LL * HIDN * HW)            // NPAIR*HW*2 = 1114112
#define IMGH_OFF (DISP_OFF + NPAIR * HW * 2)         // bf16 imgs: LL*CC*HW/2 = 1048576
#define A_OFF    (IMGH_OFF + LL * CC * HW / 2)       // 40*CC*HW = 5242880
// total ~ 9.6M floats (~38.5 MB)

// ---- pair tables for disp ----
__device__ const int T_PAIR[NPAIR] = {
    0, 1,1, 2,2,2, 3,3,3,3, 4,4,4,4,4, 5,5,5,5,5,5,
    6,6,6,6,6,6,6, 7,7,7,7,7,7,7,7,
    8,8,8,8,8,8,8,8,8, 9,9,9,9,9,9,9,9,9,9,
    10,10,10,10,10,10,10,10,10,10,10,
    11,11,11,11,11,11,11,11,11,11,11,11,
    12,12,12,12,12,12,12,12,12,12,12,12,12,
    13,13,13,13,13,13,13,13,13,13,13,13,13,13,
    14,14,14,14,14,14,14,14,14,14,14,14,14,14,14,
    15,15,15,15,15,15,15,15,15,15,15,15,15,15,15,15 };
__device__ const int K_PAIR[NPAIR] = {
    0, 0,1, 0,1,2, 0,1,2,3, 0,1,2,3,4, 0,1,2,3,4,5,
    0,1,2,3,4,5,6, 0,1,2,3,4,5,6,7,
    0,1,2,3,4,5,6,7,8, 0,1,2,3,4,5,6,7,8,9,
    0,1,2,3,4,5,6,7,8,9,10,
    0,1,2,3,4,5,6,7,8,9,10,11,
    0,1,2,3,4,5,6,7,8,9,10,11,12,
    0,1,2,3,4,5,6,7,8,9,10,11,12,13,
    0,1,2,3,4,5,6,7,8,9,10,11,12,13,14,
    0,1,2,3,4,5,6,7,8,9,10,11,12,13,14,15 };
__device__ const int TRI[LL] = {0,1,3,6,10,15,21,28,36,45,55,66,78,91,105,120};

// ---- chunk tables, SORTED by k-chunk (KC) then t, for XCD locality ----
// KC0: t=0..15 (16), KC1: t=4..15 (12), KC2: t=8..15 (8), KC3: t=12..15 (4)
__device__ const int T_SORT[NCHUNK] = {
    0,1,2,3,4,5,6,7,8,9,10,11,12,13,14,15,
    4,5,6,7,8,9,10,11,12,13,14,15,
    8,9,10,11,12,13,14,15,
    12,13,14,15 };
__device__ const int KC_SORT[NCHUNK] = {
    0,0,0,0,0,0,0,0,0,0,0,0,0,0,0,0,
    1,1,1,1,1,1,1,1,1,1,1,1,
    2,2,2,2,2,2,2,2,
    3,3,3,3 };
// reduce: chunk index for (t, kc) = SEG[kc] + (t - TMIN[kc])
__device__ const int SEG[4]  = {0, 16, 28, 36};
__device__ const int TMIN[4] = {0, 4, 8, 12};

__device__ inline unsigned short f2bf(float f) {   // RNE fp32 -> bf16
    unsigned u = __float_as_uint(f);
    unsigned r = (u + 0x7fffu + ((u >> 16) & 1u)) >> 16;
    return (unsigned short)r;
}
__device__ inline float bf2f(unsigned short h) {
    return __uint_as_float(((unsigned)h) << 16);
}

// ---------------- cumsum of flows over L ----------------
__global__ __launch_bounds__(256) void cumsum_kernel(const float* __restrict__ flows,
                                                     float* __restrict__ cum) {
    int idx = blockIdx.x * 256 + threadIdx.x;
    float acc = 0.0f;
#pragma unroll
    for (int l = 0; l < LL; ++l) {
        acc += flows[l * 2 * HW + idx];
        cum[l * 2 * HW + idx] = acc;
    }
}

// ---------------- prep: U/V halves (channel-first) + bf16 image copy ----------------
__global__ __launch_bounds__(256) void prep_kernel(const float* __restrict__ images,
                                                   const float* __restrict__ w1,
                                                   const float* __restrict__ b1,
                                                   float* __restrict__ ws) {
    __shared__ float w1s[HIDN * 2 * CC];
    const int tid = threadIdx.x;
    ((float4*)w1s)[tid] = ((const float4*)w1)[tid];
    __syncthreads();

    const int l  = blockIdx.y;
    const int px = blockIdx.x * 256 + tid;
    const float* img = images + (size_t)l * CC * HW;
    unsigned short* imh = (unsigned short*)(ws + IMGH_OFF) + (size_t)l * CC * HW;

    float u[HIDN], v[HIDN];
#pragma unroll
    for (int o = 0; o < HIDN; ++o) { u[o] = 0.0f; v[o] = b1[o]; }

#pragma unroll
    for (int c = 0; c < CC; ++c) {
        float x = img[c * HW + px];           // coalesced
        imh[c * HW + px] = f2bf(x);           // bf16 copy, coalesced
#pragma unroll
        for (int o = 0; o < HIDN; ++o) {
            u[o] = fmaf(w1s[o * 64 + c],      x, u[o]);
            v[o] = fmaf(w1s[o * 64 + CC + c], x, v[o]);
        }
    }

    float* Up = ws + U_OFF + (size_t)l * HIDN * HW + px;
    float* Vp = ws + V_OFF + (size_t)l * HIDN * HW + px;
#pragma unroll
    for (int o = 0; o < HIDN; ++o) {
        Up[o * HW] = u[o];
        Vp[o * HW] = v[o];
    }
}

// ---------------- disp: per (t,k) pair, displacement = (cum_t - cum_k) + res ----
__global__ __launch_bounds__(256) void disp_kernel(float* __restrict__ ws,
                                                   const float* __restrict__ w2,
                                                   const float* __restrict__ b2) {
    __shared__ float w2s[2 * HIDN];
    __shared__ float b2s2[2];
    const int tid = threadIdx.x;
    if (tid < 2 * HIDN) w2s[tid] = w2[tid];
    if (tid < 2)        b2s2[tid] = b2[tid];
    __syncthreads();

    const int pair = blockIdx.y;
    const int t = T_PAIR[pair];
    const int k = K_PAIR[pair];
    const int px = blockIdx.x * 256 + tid;

    const float* cum = ws + CUM_OFF;
    const float* up  = ws + U_OFF + (size_t)t * HIDN * HW + px;
    const float* vp  = ws + V_OFF + (size_t)k * HIDN * HW + px;

    float res0 = b2s2[0], res1 = b2s2[1];
#pragma unroll
    for (int o = 0; o < HIDN; ++o) {
        float h = fmaxf(up[o * HW] + vp[o * HW], 0.0f);
        res0 = fmaf(w2s[o],        h, res0);
        res1 = fmaf(w2s[HIDN + o], h, res1);
    }

    float dx = (cum[(t * 2)     * HW + px] - cum[(k * 2)     * HW + px]) + res0;
    float dy = (cum[(t * 2 + 1) * HW + px] - cum[(k * 2 + 1) * HW + px]) + res1;

    ((float2*)(ws + DISP_OFF))[(size_t)pair * HW + px] = make_float2(dx, dy);
}

// ---------------- phase A: sample, XCD-pinned k-chunks, bf16 gathers ----------------
// grid: 2560 linear blocks. Swizzle: s=(i%8)*320+i/8 over (chunk-sorted, strip) order
// block: 256 = 64 px x 4 channel-groups of 8
__global__ __launch_bounds__(256) void sample_kernel(const float* __restrict__ ws_in,
                                                     float* __restrict__ ws_out,
                                                     const float* __restrict__ decay_log) {
    const int tid = threadIdx.x;
    const int hwb = blockIdx.x;                    // hardware dispatch index
    const int s   = (hwb & 7) * 320 + (hwb >> 3);  // XCD-pinning permutation
    const int cid = s >> 6;                        // sorted chunk id 0..39
    const int strip = s & 63;                      // image row
    const int t   = T_SORT[cid];
    const int k0  = KC_SORT[cid] * 4;

    const int lane = tid & 63;        // x coord
    const int cg   = tid >> 6;        // channel group (one per wave)
    const int c0   = cg * 8;
    const int px   = strip * 64 + lane;

    const float2* disp2 = (const float2*)(ws_in + DISP_OFF);
    const unsigned short* imh = (const unsigned short*)(ws_in + IMGH_OFF);

    const float lam = expf(decay_log[0]);
    const float bgx = (float)(2 * lane  + 1) * (1.0f / 64.0f) - 1.0f;
    const float bgy = (float)(2 * strip + 1) * (1.0f / 64.0f) - 1.0f;

    float acc[8];
#pragma unroll
    for (int j = 0; j < 8; ++j) acc[j] = 0.0f;

#pragma unroll
    for (int dk = 0; dk < 4; ++dk) {
        const int k = k0 + dk;
        if (k > t) break;   // uniform across block; k increasing

        float2 d = disp2[(size_t)(TRI[t] + k) * HW + px];
        float gx = bgx + d.x;
        float gy = bgy + d.y;

        // wrap x: mod(gx+1, 2) - 1 (floor-mod)
        float xp = gx + 1.0f;
        xp = xp - floorf(xp * 0.5f) * 2.0f;
        float gxw = xp - 1.0f;

        float ix = ((gxw + 1.0f) * 64.0f - 1.0f) * 0.5f;
        float iy = ((gy  + 1.0f) * 64.0f - 1.0f) * 0.5f;

        float ix0f = floorf(ix), iy0f = floorf(iy);
        float fx1 = ix - ix0f, fy1 = iy - iy0f;
        float fx0 = 1.0f - fx1, fy0 = 1.0f - fy1;
        int ix0 = (int)ix0f, iy0 = (int)iy0f;
        int ix1 = ix0 + 1,   iy1 = iy0 + 1;

        const float wt = expf(-lam * (float)(t - k));

        int   off[4];
        float cwt[4];
        {
            int xi[4] = {ix0, ix1, ix0, ix1};
            int yi[4] = {iy0, iy0, iy1, iy1};
            float wwv[4] = {fx0 * fy0, fx1 * fy0, fx0 * fy1, fx1 * fy1};
#pragma unroll
            for (int j = 0; j < 4; ++j) {
                bool valid = (xi[j] >= 0) & (xi[j] < WW) & (yi[j] >= 0) & (yi[j] < HH);
                int xc = min(max(xi[j], 0), WW - 1);
                int yc = min(max(yi[j], 0), HH - 1);
                off[j] = yc * WW + xc;
                cwt[j] = valid ? wwv[j] * wt : 0.0f;
            }
        }

        const float w0 = cwt[0], w1v = cwt[1], w2v = cwt[2], w3v = cwt[3];
        const unsigned short* kb = imh + ((size_t)k * CC + c0) * HW;
#pragma unroll
        for (int j = 0; j < 8; ++j) {
            const unsigned short* pl = kb + j * HW;
            float sv = w0 * bf2f(pl[off[0]]) + w1v * bf2f(pl[off[1]])
                     + w2v * bf2f(pl[off[2]]) + w3v * bf2f(pl[off[3]]);
            acc[j] += sv;
        }
    }

    // store partial slice A[cid][c0+j][px] (coalesced per wave)
    float* Ap = ws_out + A_OFF + ((size_t)cid * CC + c0) * HW + px;
#pragma unroll
    for (int j = 0; j < 8; ++j) Ap[j * HW] = acc[j];
}

// ---------------- phase B: reduce over k-chunks (pure streaming) ----------------
__global__ __launch_bounds__(256) void reduce_kernel(const float* __restrict__ ws,
                                                     float* __restrict__ out) {
    const int gid = blockIdx.x * 256 + threadIdx.x;  // 0..524287
    const int t   = gid >> 15;                        // 32768 float4 per t
    const int c   = (gid >> 10) & 31;
    const int px4 = gid & 1023;

    const float4* A4 = (const float4*)(ws + A_OFF);
    const int n = 1 + (t >= 4) + (t >= 8) + (t >= 12);

    float4 s = make_float4(0.0f, 0.0f, 0.0f, 0.0f);
    for (int kc = 0; kc < n; ++kc) {
        int cid = SEG[kc] + (t - TMIN[kc]);
        float4 a = A4[((size_t)cid * CC + c) * (HW / 4) + px4];
        s.x += a.x; s.y += a.y; s.z += a.z; s.w += a.w;
    }
    ((float4*)out)[gid] = s;
}

extern "C" void kernel_launch(void* const* d_in, const int* in_sizes, int n_in,
                              void* d_out, int out_size, void* d_ws, size_t ws_size,
                              hipStream_t stream) {
    const float* flows     = (const float*)d_in[0];
    const float* images    = (const float*)d_in[1];
    const float* decay_log = (const float*)d_in[2];
    const float* w1        = (const float*)d_in[3];
    const float* b1        = (const float*)d_in[4];
    const float* w2        = (const float*)d_in[5];
    const float* b2        = (const float*)d_in[6];
    float* out = (float*)d_out;
    float* ws  = (float*)d_ws;

    cumsum_kernel<<<dim3(2 * HW / 256), dim3(256), 0, stream>>>(flows, ws + CUM_OFF);

    prep_kernel<<<dim3(HW / 256, LL), dim3(256), 0, stream>>>(images, w1, b1, ws);

    disp_kernel<<<dim3(HW / 256, NPAIR), dim3(256), 0, stream>>>(ws, w2, b2);

    sample_kernel<<<dim3(8 * 320), dim3(256), 0, stream>>>(ws, ws, decay_log);

    reduce_kernel<<<dim3(2048), dim3(256), 0, stream>>>(ws, out);
}

// Round 9
// 161.294 us; speedup vs baseline: 1.0679x; 1.0038x over previous
//
#include <hip/hip_runtime.h>

#define LL 16
#define CC 32
#define HIDN 16
#define HH 64
#define WW 64
#define HW 4096    // 64*64
#define NPAIR 136  // (t,k) with k<=t
#define NCHUNK 40  // (t, k-chunk-of-4) pairs

// ws layout (floats):
#define CUM_OFF  0                                   // 131072
#define U_OFF    (LL * 2 * HW)                       // 1048576
#define V_OFF    (U_OFF + LL * HIDN * HW)            // 1048576
#define DISP_OFF (V_OFF + LL * HIDN * HW)            // NPAIR*HW*2 = 1114112
#define IMGH_OFF (DISP_OFF + NPAIR * HW * 2)         // bf16 imgs: LL*CC*HW/2 = 1048576
#define A_OFF    (IMGH_OFF + LL * CC * HW / 2)       // 40*CC*HW = 5242880

// ---- pair tables for disp ----
__device__ const int T_PAIR[NPAIR] = {
    0, 1,1, 2,2,2, 3,3,3,3, 4,4,4,4,4, 5,5,5,5,5,5,
    6,6,6,6,6,6,6, 7,7,7,7,7,7,7,7,
    8,8,8,8,8,8,8,8,8, 9,9,9,9,9,9,9,9,9,9,
    10,10,10,10,10,10,10,10,10,10,10,
    11,11,11,11,11,11,11,11,11,11,11,11,
    12,12,12,12,12,12,12,12,12,12,12,12,12,
    13,13,13,13,13,13,13,13,13,13,13,13,13,13,
    14,14,14,14,14,14,14,14,14,14,14,14,14,14,14,
    15,15,15,15,15,15,15,15,15,15,15,15,15,15,15,15 };
__device__ const int K_PAIR[NPAIR] = {
    0, 0,1, 0,1,2, 0,1,2,3, 0,1,2,3,4, 0,1,2,3,4,5,
    0,1,2,3,4,5,6, 0,1,2,3,4,5,6,7,
    0,1,2,3,4,5,6,7,8, 0,1,2,3,4,5,6,7,8,9,
    0,1,2,3,4,5,6,7,8,9,10,
    0,1,2,3,4,5,6,7,8,9,10,11,
    0,1,2,3,4,5,6,7,8,9,10,11,12,
    0,1,2,3,4,5,6,7,8,9,10,11,12,13,
    0,1,2,3,4,5,6,7,8,9,10,11,12,13,14,
    0,1,2,3,4,5,6,7,8,9,10,11,12,13,14,15 };
__device__ const int TRI[LL] = {0,1,3,6,10,15,21,28,36,45,55,66,78,91,105,120};

// ---- chunk tables, SORTED by k-chunk (KC) then t, for XCD locality ----
__device__ const int T_SORT[NCHUNK] = {
    0,1,2,3,4,5,6,7,8,9,10,11,12,13,14,15,
    4,5,6,7,8,9,10,11,12,13,14,15,
    8,9,10,11,12,13,14,15,
    12,13,14,15 };
__device__ const int KC_SORT[NCHUNK] = {
    0,0,0,0,0,0,0,0,0,0,0,0,0,0,0,0,
    1,1,1,1,1,1,1,1,1,1,1,1,
    2,2,2,2,2,2,2,2,
    3,3,3,3 };
// reduce: chunk index for (t, kc) = SEG[kc] + (t - TMIN[kc])
__device__ const int SEG[4]  = {0, 16, 28, 36};
__device__ const int TMIN[4] = {0, 4, 8, 12};

__device__ inline unsigned short f2bf(float f) {   // RNE fp32 -> bf16
    unsigned u = __float_as_uint(f);
    unsigned r = (u + 0x7fffu + ((u >> 16) & 1u)) >> 16;
    return (unsigned short)r;
}
__device__ inline float bf2f(unsigned short h) {
    return __uint_as_float(((unsigned)h) << 16);
}

// ---------------- cumsum of flows over L ----------------
__global__ __launch_bounds__(256) void cumsum_kernel(const float* __restrict__ flows,
                                                     float* __restrict__ cum) {
    int idx = blockIdx.x * 256 + threadIdx.x;
    float acc = 0.0f;
#pragma unroll
    for (int l = 0; l < LL; ++l) {
        acc += flows[l * 2 * HW + idx];
        cum[l * 2 * HW + idx] = acc;
    }
}

// ---------------- prep: U/V halves (channel-first) + bf16 image copy ----------------
__global__ __launch_bounds__(256) void prep_kernel(const float* __restrict__ images,
                                                   const float* __restrict__ w1,
                                                   const float* __restrict__ b1,
                                                   float* __restrict__ ws) {
    __shared__ float w1s[HIDN * 2 * CC];
    const int tid = threadIdx.x;
    ((float4*)w1s)[tid] = ((const float4*)w1)[tid];
    __syncthreads();

    const int l  = blockIdx.y;
    const int px = blockIdx.x * 256 + tid;
    const float* img = images + (size_t)l * CC * HW;
    unsigned short* imh = (unsigned short*)(ws + IMGH_OFF) + (size_t)l * CC * HW;

    float u[HIDN], v[HIDN];
#pragma unroll
    for (int o = 0; o < HIDN; ++o) { u[o] = 0.0f; v[o] = b1[o]; }

#pragma unroll
    for (int c = 0; c < CC; ++c) {
        float x = img[c * HW + px];           // coalesced
        imh[c * HW + px] = f2bf(x);           // bf16 copy, coalesced
#pragma unroll
        for (int o = 0; o < HIDN; ++o) {
            u[o] = fmaf(w1s[o * 64 + c],      x, u[o]);
            v[o] = fmaf(w1s[o * 64 + CC + c], x, v[o]);
        }
    }

    float* Up = ws + U_OFF + (size_t)l * HIDN * HW + px;
    float* Vp = ws + V_OFF + (size_t)l * HIDN * HW + px;
#pragma unroll
    for (int o = 0; o < HIDN; ++o) {
        Up[o * HW] = u[o];
        Vp[o * HW] = v[o];
    }
}

// ---------------- disp: per (t,k) pair, displacement = (cum_t - cum_k) + res ----
__global__ __launch_bounds__(256) void disp_kernel(float* __restrict__ ws,
                                                   const float* __restrict__ w2,
                                                   const float* __restrict__ b2) {
    __shared__ float w2s[2 * HIDN];
    __shared__ float b2s2[2];
    const int tid = threadIdx.x;
    if (tid < 2 * HIDN) w2s[tid] = w2[tid];
    if (tid < 2)        b2s2[tid] = b2[tid];
    __syncthreads();

    const int pair = blockIdx.y;
    const int t = T_PAIR[pair];
    const int k = K_PAIR[pair];
    const int px = blockIdx.x * 256 + tid;

    const float* cum = ws + CUM_OFF;
    const float* up  = ws + U_OFF + (size_t)t * HIDN * HW + px;
    const float* vp  = ws + V_OFF + (size_t)k * HIDN * HW + px;

    float res0 = b2s2[0], res1 = b2s2[1];
#pragma unroll
    for (int o = 0; o < HIDN; ++o) {
        float h = fmaxf(up[o * HW] + vp[o * HW], 0.0f);
        res0 = fmaf(w2s[o],        h, res0);
        res1 = fmaf(w2s[HIDN + o], h, res1);
    }

    float dx = (cum[(t * 2)     * HW + px] - cum[(k * 2)     * HW + px]) + res0;
    float dy = (cum[(t * 2 + 1) * HW + px] - cum[(k * 2 + 1) * HW + px]) + res1;

    ((float2*)(ws + DISP_OFF))[(size_t)pair * HW + px] = make_float2(dx, dy);
}

// ---------------- phase A: sample, predicated 4-deep k pipeline ----------------
// grid: 2560 linear blocks; s=(i%8)*320+i/8 pins k-chunk windows to XCDs
// block: 256 = 64 px x 4 channel-groups of 8
__global__ __launch_bounds__(256) void sample_kernel(const float* __restrict__ ws_in,
                                                     float* __restrict__ ws_out,
                                                     const float* __restrict__ decay_log) {
    const int tid = threadIdx.x;
    const int hwb = blockIdx.x;
    const int s   = (hwb & 7) * 320 + (hwb >> 3);  // XCD-pinning permutation
    const int cid = s >> 6;                        // sorted chunk id 0..39
    const int strip = s & 63;                      // image row
    const int t   = T_SORT[cid];
    const int k0  = KC_SORT[cid] * 4;

    const int lane = tid & 63;        // x coord
    const int cg   = tid >> 6;        // channel group (one per wave)
    const int c0   = cg * 8;
    const int px   = strip * 64 + lane;

    const float2* disp2 = (const float2*)(ws_in + DISP_OFF);
    const unsigned short* imh = (const unsigned short*)(ws_in + IMGH_OFF);

    const float lam = expf(decay_log[0]);
    const float bgx = (float)(2 * lane  + 1) * (1.0f / 64.0f) - 1.0f;
    const float bgy = (float)(2 * strip + 1) * (1.0f / 64.0f) - 1.0f;

    // ---- stage 1: all 4 disp loads + decay weights (no branches) ----
    float2 dd[4];
    float  wts[4];
#pragma unroll
    for (int dk = 0; dk < 4; ++dk) {
        const int k   = k0 + dk;
        const int kcl = (k <= t) ? k : t;             // clamp to a valid pair
        dd[dk]  = disp2[(size_t)(TRI[t] + kcl) * HW + px];
        wts[dk] = (k <= t) ? expf(-lam * (float)(t - k)) : 0.0f;
    }

    // ---- stage 2: all 4 offset/weight sets ----
    int   off[4][4];
    float cwt[4][4];
#pragma unroll
    for (int dk = 0; dk < 4; ++dk) {
        float gx = bgx + dd[dk].x;
        float gy = bgy + dd[dk].y;

        // wrap x: mod(gx+1, 2) - 1 (floor-mod)
        float xp = gx + 1.0f;
        xp = xp - floorf(xp * 0.5f) * 2.0f;
        float gxw = xp - 1.0f;

        float ix = ((gxw + 1.0f) * 64.0f - 1.0f) * 0.5f;
        float iy = ((gy  + 1.0f) * 64.0f - 1.0f) * 0.5f;

        float ix0f = floorf(ix), iy0f = floorf(iy);
        float fx1 = ix - ix0f, fy1 = iy - iy0f;
        float fx0 = 1.0f - fx1, fy0 = 1.0f - fy1;
        int ix0 = (int)ix0f, iy0 = (int)iy0f;
        int ix1 = ix0 + 1,   iy1 = iy0 + 1;

        int xi[4] = {ix0, ix1, ix0, ix1};
        int yi[4] = {iy0, iy0, iy1, iy1};
        float wwv[4] = {fx0 * fy0, fx1 * fy0, fx0 * fy1, fx1 * fy1};
#pragma unroll
        for (int j = 0; j < 4; ++j) {
            bool valid = (xi[j] >= 0) & (xi[j] < WW) & (yi[j] >= 0) & (yi[j] < HH);
            int xc = min(max(xi[j], 0), WW - 1);
            int yc = min(max(yi[j], 0), HH - 1);
            off[dk][j] = yc * WW + xc;
            cwt[dk][j] = valid ? wwv[j] * wts[dk] : 0.0f;
        }
    }

    // ---- stage 3: all 128 gathers (independent) + accumulate ----
    float acc[8];
#pragma unroll
    for (int j = 0; j < 8; ++j) acc[j] = 0.0f;

#pragma unroll
    for (int dk = 0; dk < 4; ++dk) {
        const unsigned short* kb = imh + ((size_t)(k0 + dk) * CC + c0) * HW;
        const float w0 = cwt[dk][0], w1v = cwt[dk][1];
        const float w2v = cwt[dk][2], w3v = cwt[dk][3];
#pragma unroll
        for (int j = 0; j < 8; ++j) {
            const unsigned short* pl = kb + j * HW;
            float sv = w0 * bf2f(pl[off[dk][0]]) + w1v * bf2f(pl[off[dk][1]])
                     + w2v * bf2f(pl[off[dk][2]]) + w3v * bf2f(pl[off[dk][3]]);
            acc[j] += sv;
        }
    }

    // store partial slice A[cid][c0+j][px] (coalesced per wave)
    float* Ap = ws_out + A_OFF + ((size_t)cid * CC + c0) * HW + px;
#pragma unroll
    for (int j = 0; j < 8; ++j) Ap[j * HW] = acc[j];
}

// ---------------- phase B: reduce over k-chunks (pure streaming) ----------------
__global__ __launch_bounds__(256) void reduce_kernel(const float* __restrict__ ws,
                                                     float* __restrict__ out) {
    const int gid = blockIdx.x * 256 + threadIdx.x;  // 0..524287
    const int t   = gid >> 15;                        // 32768 float4 per t
    const int c   = (gid >> 10) & 31;
    const int px4 = gid & 1023;

    const float4* A4 = (const float4*)(ws + A_OFF);
    const int n = 1 + (t >= 4) + (t >= 8) + (t >= 12);

    float4 s = make_float4(0.0f, 0.0f, 0.0f, 0.0f);
    for (int kc = 0; kc < n; ++kc) {
        int cid = SEG[kc] + (t - TMIN[kc]);
        float4 a = A4[((size_t)cid * CC + c) * (HW / 4) + px4];
        s.x += a.x; s.y += a.y; s.z += a.z; s.w += a.w;
    }
    ((float4*)out)[gid] = s;
}

extern "C" void kernel_launch(void* const* d_in, const int* in_sizes, int n_in,
                              void* d_out, int out_size, void* d_ws, size_t ws_size,
                              hipStream_t stream) {
    const float* flows     = (const float*)d_in[0];
    const float* images    = (const float*)d_in[1];
    const float* decay_log = (const float*)d_in[2];
    const float* w1        = (const float*)d_in[3];
    const float* b1        = (const float*)d_in[4];
    const float* w2        = (const float*)d_in[5];
    const float* b2        = (const float*)d_in[6];
    float* out = (float*)d_out;
    float* ws  = (float*)d_ws;

    cumsum_kernel<<<dim3(2 * HW / 256), dim3(256), 0, stream>>>(flows, ws + CUM_OFF);

    prep_kernel<<<dim3(HW / 256, LL), dim3(256), 0, stream>>>(images, w1, b1, ws);

    disp_kernel<<<dim3(HW / 256, NPAIR), dim3(256), 0, stream>>>(ws, w2, b2);

    sample_kernel<<<dim3(8 * 320), dim3(256), 0, stream>>>(ws, ws, decay_log);

    reduce_kernel<<<dim3(2048), dim3(256), 0, stream>>>(ws, out);
}

// Round 10
// 115.310 us; speedup vs baseline: 1.4937x; 1.3988x over previous
//
#include <hip/hip_runtime.h>

#define LL 16
#define CC 32
#define HIDN 16
#define HH 64
#define WW 64
#define HW 4096    // 64*64
#define NPAIR 136  // (t,k) with k<=t
#define NCHUNK 40  // (t, k-chunk-of-4) pairs

// ws layout (floats):
#define CUM_OFF  0                                   // 131072
#define U_OFF    (LL * 2 * HW)                       // 1048576
#define V_OFF    (U_OFF + LL * HIDN * HW)            // 1048576
#define DISP_OFF (V_OFF + LL * HIDN * HW)            // NPAIR*HW*2 = 1114112
#define IMGC_OFF (DISP_OFF + NPAIR * HW * 2)         // bf16 ch-grouped: LL*CC*HW/2 = 1048576
#define A_OFF    (IMGC_OFF + LL * CC * HW / 2)       // 40*CC*HW = 5242880

// ---- pair tables for disp ----
__device__ const int T_PAIR[NPAIR] = {
    0, 1,1, 2,2,2, 3,3,3,3, 4,4,4,4,4, 5,5,5,5,5,5,
    6,6,6,6,6,6,6, 7,7,7,7,7,7,7,7,
    8,8,8,8,8,8,8,8,8, 9,9,9,9,9,9,9,9,9,9,
    10,10,10,10,10,10,10,10,10,10,10,
    11,11,11,11,11,11,11,11,11,11,11,11,
    12,12,12,12,12,12,12,12,12,12,12,12,12,
    13,13,13,13,13,13,13,13,13,13,13,13,13,13,
    14,14,14,14,14,14,14,14,14,14,14,14,14,14,14,
    15,15,15,15,15,15,15,15,15,15,15,15,15,15,15,15 };
__device__ const int K_PAIR[NPAIR] = {
    0, 0,1, 0,1,2, 0,1,2,3, 0,1,2,3,4, 0,1,2,3,4,5,
    0,1,2,3,4,5,6, 0,1,2,3,4,5,6,7,
    0,1,2,3,4,5,6,7,8, 0,1,2,3,4,5,6,7,8,9,
    0,1,2,3,4,5,6,7,8,9,10,
    0,1,2,3,4,5,6,7,8,9,10,11,
    0,1,2,3,4,5,6,7,8,9,10,11,12,
    0,1,2,3,4,5,6,7,8,9,10,11,12,13,
    0,1,2,3,4,5,6,7,8,9,10,11,12,13,14,
    0,1,2,3,4,5,6,7,8,9,10,11,12,13,14,15 };
__device__ const int TRI[LL] = {0,1,3,6,10,15,21,28,36,45,55,66,78,91,105,120};

// ---- chunk tables, SORTED by k-chunk (KC) then t, for XCD locality ----
__device__ const int T_SORT[NCHUNK] = {
    0,1,2,3,4,5,6,7,8,9,10,11,12,13,14,15,
    4,5,6,7,8,9,10,11,12,13,14,15,
    8,9,10,11,12,13,14,15,
    12,13,14,15 };
__device__ const int KC_SORT[NCHUNK] = {
    0,0,0,0,0,0,0,0,0,0,0,0,0,0,0,0,
    1,1,1,1,1,1,1,1,1,1,1,1,
    2,2,2,2,2,2,2,2,
    3,3,3,3 };
// reduce: chunk index for (t, kc) = SEG[kc] + (t - TMIN[kc])
__device__ const int SEG[4]  = {0, 16, 28, 36};
__device__ const int TMIN[4] = {0, 4, 8, 12};

__device__ inline unsigned short f2bf(float f) {   // RNE fp32 -> bf16
    unsigned u = __float_as_uint(f);
    unsigned r = (u + 0x7fffu + ((u >> 16) & 1u)) >> 16;
    return (unsigned short)r;
}
__device__ inline float bflo(unsigned u) { return __uint_as_float(u << 16); }
__device__ inline float bfhi(unsigned u) { return __uint_as_float(u & 0xffff0000u); }

// ---------------- cumsum of flows over L ----------------
__global__ __launch_bounds__(256) void cumsum_kernel(const float* __restrict__ flows,
                                                     float* __restrict__ cum) {
    int idx = blockIdx.x * 256 + threadIdx.x;
    float acc = 0.0f;
#pragma unroll
    for (int l = 0; l < LL; ++l) {
        acc += flows[l * 2 * HW + idx];
        cum[l * 2 * HW + idx] = acc;
    }
}

// ---------------- prep: U/V (channel-first) + bf16 channel-group-8 image copy ----
// imgc layout: [(l*4+cg)][px][8ch] as uint4 (8 bf16 = 16B) per (px)
__global__ __launch_bounds__(256) void prep_kernel(const float* __restrict__ images,
                                                   const float* __restrict__ w1,
                                                   const float* __restrict__ b1,
                                                   float* __restrict__ ws) {
    __shared__ float w1s[HIDN * 2 * CC];
    const int tid = threadIdx.x;
    ((float4*)w1s)[tid] = ((const float4*)w1)[tid];
    __syncthreads();

    const int l  = blockIdx.y;
    const int px = blockIdx.x * 256 + tid;
    const float* img = images + (size_t)l * CC * HW;

    float x[CC];
#pragma unroll
    for (int c = 0; c < CC; ++c) x[c] = img[c * HW + px];   // coalesced

    float u[HIDN], v[HIDN];
#pragma unroll
    for (int o = 0; o < HIDN; ++o) { u[o] = 0.0f; v[o] = b1[o]; }
#pragma unroll
    for (int c = 0; c < CC; ++c) {
#pragma unroll
        for (int o = 0; o < HIDN; ++o) {
            u[o] = fmaf(w1s[o * 64 + c],      x[c], u[o]);
            v[o] = fmaf(w1s[o * 64 + CC + c], x[c], v[o]);
        }
    }

    float* Up = ws + U_OFF + (size_t)l * HIDN * HW + px;
    float* Vp = ws + V_OFF + (size_t)l * HIDN * HW + px;
#pragma unroll
    for (int o = 0; o < HIDN; ++o) {
        Up[o * HW] = u[o];
        Vp[o * HW] = v[o];
    }

    // bf16 channel-group-8 copy: plane (l*4+cg), 16B per px
    uint4* img4 = (uint4*)(ws + IMGC_OFF);
#pragma unroll
    for (int cg = 0; cg < 4; ++cg) {
        const int c0 = cg * 8;
        unsigned d[4];
#pragma unroll
        for (int q = 0; q < 4; ++q)
            d[q] = (unsigned)f2bf(x[c0 + 2 * q]) | ((unsigned)f2bf(x[c0 + 2 * q + 1]) << 16);
        img4[((size_t)(l * 4 + cg)) * HW + px] = make_uint4(d[0], d[1], d[2], d[3]);
    }
}

// ---------------- disp: per (t,k) pair, displacement = (cum_t - cum_k) + res ----
__global__ __launch_bounds__(256) void disp_kernel(float* __restrict__ ws,
                                                   const float* __restrict__ w2,
                                                   const float* __restrict__ b2) {
    __shared__ float w2s[2 * HIDN];
    __shared__ float b2s2[2];
    const int tid = threadIdx.x;
    if (tid < 2 * HIDN) w2s[tid] = w2[tid];
    if (tid < 2)        b2s2[tid] = b2[tid];
    __syncthreads();

    const int pair = blockIdx.y;
    const int t = T_PAIR[pair];
    const int k = K_PAIR[pair];
    const int px = blockIdx.x * 256 + tid;

    const float* cum = ws + CUM_OFF;
    const float* up  = ws + U_OFF + (size_t)t * HIDN * HW + px;
    const float* vp  = ws + V_OFF + (size_t)k * HIDN * HW + px;

    float res0 = b2s2[0], res1 = b2s2[1];
#pragma unroll
    for (int o = 0; o < HIDN; ++o) {
        float h = fmaxf(up[o * HW] + vp[o * HW], 0.0f);
        res0 = fmaf(w2s[o],        h, res0);
        res1 = fmaf(w2s[HIDN + o], h, res1);
    }

    float dx = (cum[(t * 2)     * HW + px] - cum[(k * 2)     * HW + px]) + res0;
    float dy = (cum[(t * 2 + 1) * HW + px] - cum[(k * 2 + 1) * HW + px]) + res1;

    ((float2*)(ws + DISP_OFF))[(size_t)pair * HW + px] = make_float2(dx, dy);
}

// ---------------- phase A: sample, 16 x dwordx4 gathers (8ch each) ----------------
// grid: 2560 linear blocks; s=(i%8)*320+i/8 pins k-chunk windows to XCDs
// block: 256 = 64 px x 4 channel-groups of 8; wave = 64 adjacent px, one cg
__global__ __launch_bounds__(256, 2) void sample_kernel(const float* __restrict__ ws_in,
                                                        float* __restrict__ ws_out,
                                                        const float* __restrict__ decay_log) {
    const int tid = threadIdx.x;
    const int hwb = blockIdx.x;
    const int s   = (hwb & 7) * 320 + (hwb >> 3);  // XCD-pinning permutation
    const int cid = s >> 6;                        // sorted chunk id 0..39
    const int strip = s & 63;                      // image row
    const int t   = T_SORT[cid];
    const int k0  = KC_SORT[cid] * 4;

    const int lane = tid & 63;        // x coord
    const int cg   = tid >> 6;        // channel group (one per wave)
    const int px   = strip * 64 + lane;

    const float2* disp2 = (const float2*)(ws_in + DISP_OFF);
    const uint4*  img4  = (const uint4*)(ws_in + IMGC_OFF);

    const float lam = expf(decay_log[0]);
    const float bgx = (float)(2 * lane  + 1) * (1.0f / 64.0f) - 1.0f;
    const float bgy = (float)(2 * strip + 1) * (1.0f / 64.0f) - 1.0f;

    // ---- stage 1: all 4 disp loads + decay weights (no branches) ----
    float2 dd[4];
    float  wts[4];
#pragma unroll
    for (int dk = 0; dk < 4; ++dk) {
        const int k   = k0 + dk;
        const int kcl = (k <= t) ? k : t;             // clamp to a valid pair
        dd[dk]  = disp2[(size_t)(TRI[t] + kcl) * HW + px];
        wts[dk] = (k <= t) ? expf(-lam * (float)(t - k)) : 0.0f;
    }

    // ---- stage 2: all 4 offset/weight sets ----
    int   off[4][4];
    float cwt[4][4];
#pragma unroll
    for (int dk = 0; dk < 4; ++dk) {
        float gx = bgx + dd[dk].x;
        float gy = bgy + dd[dk].y;

        // wrap x: mod(gx+1, 2) - 1 (floor-mod)
        float xp = gx + 1.0f;
        xp = xp - floorf(xp * 0.5f) * 2.0f;
        float gxw = xp - 1.0f;

        float ix = ((gxw + 1.0f) * 64.0f - 1.0f) * 0.5f;
        float iy = ((gy  + 1.0f) * 64.0f - 1.0f) * 0.5f;

        float ix0f = floorf(ix), iy0f = floorf(iy);
        float fx1 = ix - ix0f, fy1 = iy - iy0f;
        float fx0 = 1.0f - fx1, fy0 = 1.0f - fy1;
        int ix0 = (int)ix0f, iy0 = (int)iy0f;
        int ix1 = ix0 + 1,   iy1 = iy0 + 1;

        int xi[4] = {ix0, ix1, ix0, ix1};
        int yi[4] = {iy0, iy0, iy1, iy1};
        float wwv[4] = {fx0 * fy0, fx1 * fy0, fx0 * fy1, fx1 * fy1};
#pragma unroll
        for (int j = 0; j < 4; ++j) {
            bool valid = (xi[j] >= 0) & (xi[j] < WW) & (yi[j] >= 0) & (yi[j] < HH);
            int xc = min(max(xi[j], 0), WW - 1);
            int yc = min(max(yi[j], 0), HH - 1);
            off[dk][j] = yc * WW + xc;
            cwt[dk][j] = valid ? wwv[j] * wts[dk] : 0.0f;
        }
    }

    // ---- stage 3: 16 independent dwordx4 gathers (frame k always valid) ----
    uint4 q[4][4];
#pragma unroll
    for (int dk = 0; dk < 4; ++dk) {
        const size_t pb = (size_t)((k0 + dk) * 4 + cg) * HW;
#pragma unroll
        for (int j = 0; j < 4; ++j)
            q[dk][j] = img4[pb + off[dk][j]];
    }

    float acc[8];
#pragma unroll
    for (int j = 0; j < 8; ++j) acc[j] = 0.0f;

#pragma unroll
    for (int dk = 0; dk < 4; ++dk) {
#pragma unroll
        for (int j = 0; j < 4; ++j) {
            const float wj = cwt[dk][j];
            const uint4 v = q[dk][j];
            acc[0] = fmaf(wj, bflo(v.x), acc[0]);
            acc[1] = fmaf(wj, bfhi(v.x), acc[1]);
            acc[2] = fmaf(wj, bflo(v.y), acc[2]);
            acc[3] = fmaf(wj, bfhi(v.y), acc[3]);
            acc[4] = fmaf(wj, bflo(v.z), acc[4]);
            acc[5] = fmaf(wj, bfhi(v.z), acc[5]);
            acc[6] = fmaf(wj, bflo(v.w), acc[6]);
            acc[7] = fmaf(wj, bfhi(v.w), acc[7]);
        }
    }

    // store partial slice A[cid][cg*8+j][px] (coalesced per wave)
    float* Ap = ws_out + A_OFF + ((size_t)cid * CC + cg * 8) * HW + px;
#pragma unroll
    for (int j = 0; j < 8; ++j) Ap[j * HW] = acc[j];
}

// ---------------- phase B: reduce over k-chunks (pure streaming) ----------------
__global__ __launch_bounds__(256) void reduce_kernel(const float* __restrict__ ws,
                                                     float* __restrict__ out) {
    const int gid = blockIdx.x * 256 + threadIdx.x;  // 0..524287
    const int t   = gid >> 15;                        // 32768 float4 per t
    const int c   = (gid >> 10) & 31;
    const int px4 = gid & 1023;

    const float4* A4 = (const float4*)(ws + A_OFF);
    const int n = 1 + (t >= 4) + (t >= 8) + (t >= 12);

    float4 s = make_float4(0.0f, 0.0f, 0.0f, 0.0f);
    for (int kc = 0; kc < n; ++kc) {
        int cid = SEG[kc] + (t - TMIN[kc]);
        float4 a = A4[((size_t)cid * CC + c) * (HW / 4) + px4];
        s.x += a.x; s.y += a.y; s.z += a.z; s.w += a.w;
    }
    ((float4*)out)[gid] = s;
}

extern "C" void kernel_launch(void* const* d_in, const int* in_sizes, int n_in,
                              void* d_out, int out_size, void* d_ws, size_t ws_size,
                              hipStream_t stream) {
    const float* flows     = (const float*)d_in[0];
    const float* images    = (const float*)d_in[1];
    const float* decay_log = (const float*)d_in[2];
    const float* w1        = (const float*)d_in[3];
    const float* b1        = (const float*)d_in[4];
    const float* w2        = (const float*)d_in[5];
    const float* b2        = (const float*)d_in[6];
    float* out = (float*)d_out;
    float* ws  = (float*)d_ws;

    cumsum_kernel<<<dim3(2 * HW / 256), dim3(256), 0, stream>>>(flows, ws + CUM_OFF);

    prep_kernel<<<dim3(HW / 256, LL), dim3(256), 0, stream>>>(images, w1, b1, ws);

    disp_kernel<<<dim3(HW / 256, NPAIR), dim3(256), 0, stream>>>(ws, w2, b2);

    sample_kernel<<<dim3(8 * 320), dim3(256), 0, stream>>>(ws, ws, decay_log);

    reduce_kernel<<<dim3(2048), dim3(256), 0, stream>>>(ws, out);
}

// Round 13
// 110.340 us; speedup vs baseline: 1.5610x; 1.0450x over previous
//
#include <hip/hip_runtime.h>

#define LL 16
#define CC 32
#define HIDN 16
#define HH 64
#define WW 64
#define HW 4096    // 64*64
#define NCHUNK 40  // (t, k-chunk-of-4) pairs

// ws layout (floats):
#define CUM_OFF  0                                   // 131072
#define U_OFF    (LL * 2 * HW)                       // 1048576
#define V_OFF    (U_OFF + LL * HIDN * HW)            // 1048576
#define IMGC_OFF (V_OFF + LL * HIDN * HW)            // bf16 ch-grouped: LL*CC*HW/2 = 1048576
#define A_OFF    (IMGC_OFF + LL * CC * HW / 2)       // 40*CC*HW = 5242880

// ---- chunk tables, SORTED by k-chunk (KC) then t, for XCD locality ----
__device__ const int T_SORT[NCHUNK] = {
    0,1,2,3,4,5,6,7,8,9,10,11,12,13,14,15,
    4,5,6,7,8,9,10,11,12,13,14,15,
    8,9,10,11,12,13,14,15,
    12,13,14,15 };
__device__ const int KC_SORT[NCHUNK] = {
    0,0,0,0,0,0,0,0,0,0,0,0,0,0,0,0,
    1,1,1,1,1,1,1,1,1,1,1,1,
    2,2,2,2,2,2,2,2,
    3,3,3,3 };
// reduce: chunk index for (t, kc) = SEG[kc] + (t - TMIN[kc])
__device__ const int SEG[4]  = {0, 16, 28, 36};
__device__ const int TMIN[4] = {0, 4, 8, 12};

__device__ inline unsigned short f2bf(float f) {   // RNE fp32 -> bf16
    unsigned u = __float_as_uint(f);
    unsigned r = (u + 0x7fffu + ((u >> 16) & 1u)) >> 16;
    return (unsigned short)r;
}
__device__ inline float bflo(unsigned u) { return __uint_as_float(u << 16); }
__device__ inline float bfhi(unsigned u) { return __uint_as_float(u & 0xffff0000u); }

// ---------------- cumsum of flows over L ----------------
__global__ __launch_bounds__(256) void cumsum_kernel(const float* __restrict__ flows,
                                                     float* __restrict__ cum) {
    int idx = blockIdx.x * 256 + threadIdx.x;
    float acc = 0.0f;
#pragma unroll
    for (int l = 0; l < LL; ++l) {
        acc += flows[l * 2 * HW + idx];
        cum[l * 2 * HW + idx] = acc;
    }
}

// ---------------- prep: U/V (channel-first) + bf16 channel-group-8 image copy ----
// imgc layout: [(l*4+cg)][px][8ch] as uint4 (8 bf16 = 16B) per px
__global__ __launch_bounds__(256) void prep_kernel(const float* __restrict__ images,
                                                   const float* __restrict__ w1,
                                                   const float* __restrict__ b1,
                                                   float* __restrict__ ws) {
    __shared__ float w1s[HIDN * 2 * CC];
    const int tid = threadIdx.x;
    ((float4*)w1s)[tid] = ((const float4*)w1)[tid];
    __syncthreads();

    const int l  = blockIdx.y;
    const int px = blockIdx.x * 256 + tid;
    const float* img = images + (size_t)l * CC * HW;

    float x[CC];
#pragma unroll
    for (int c = 0; c < CC; ++c) x[c] = img[c * HW + px];   // coalesced

    float u[HIDN], v[HIDN];
#pragma unroll
    for (int o = 0; o < HIDN; ++o) { u[o] = 0.0f; v[o] = b1[o]; }
#pragma unroll
    for (int c = 0; c < CC; ++c) {
#pragma unroll
        for (int o = 0; o < HIDN; ++o) {
            u[o] = fmaf(w1s[o * 64 + c],      x[c], u[o]);
            v[o] = fmaf(w1s[o * 64 + CC + c], x[c], v[o]);
        }
    }

    float* Up = ws + U_OFF + (size_t)l * HIDN * HW + px;
    float* Vp = ws + V_OFF + (size_t)l * HIDN * HW + px;
#pragma unroll
    for (int o = 0; o < HIDN; ++o) {
        Up[o * HW] = u[o];
        Vp[o * HW] = v[o];
    }

    // bf16 channel-group-8 copy: plane (l*4+cg), 16B per px
    uint4* img4 = (uint4*)(ws + IMGC_OFF);
#pragma unroll
    for (int cg = 0; cg < 4; ++cg) {
        const int c0 = cg * 8;
        unsigned d[4];
#pragma unroll
        for (int q = 0; q < 4; ++q)
            d[q] = (unsigned)f2bf(x[c0 + 2 * q]) | ((unsigned)f2bf(x[c0 + 2 * q + 1]) << 16);
        img4[((size_t)(l * 4 + cg)) * HW + px] = make_uint4(d[0], d[1], d[2], d[3]);
    }
}

// ---------------- fused sample: in-block MLP (LDS) + 16 dwordx4 gathers ----------
// grid: 2560 linear blocks; s=(i%8)*320+i/8 pins k-chunk windows to XCDs
// phase 1: 256 thr = 4 k-slots x 64 px  -> disp into LDS
// phase 2: 256 thr = 64 px x 4 channel-groups of 8 -> gathers + partial store
__global__ __launch_bounds__(256, 2) void sample_kernel(const float* __restrict__ ws_in,
                                                        float* __restrict__ ws_out,
                                                        const float* __restrict__ w2,
                                                        const float* __restrict__ b2,
                                                        const float* __restrict__ decay_log) {
    __shared__ float  w2s[2 * HIDN];
    __shared__ float  b2s2[2];
    __shared__ float2 dls[4][64];     // disp per (k-slot, px-lane)

    const int tid = threadIdx.x;
    if (tid < 2 * HIDN) w2s[tid] = w2[tid];
    if (tid < 2)        b2s2[tid] = b2[tid];
    __syncthreads();

    const int hwb = blockIdx.x;
    const int s   = (hwb & 7) * 320 + (hwb >> 3);  // XCD-pinning permutation
    const int cid = s >> 6;                        // sorted chunk id 0..39
    const int strip = s & 63;                      // image row
    const int t   = T_SORT[cid];
    const int k0  = KC_SORT[cid] * 4;

    const float* cum = ws_in + CUM_OFF;
    const float* Ub  = ws_in + U_OFF;
    const float* Vb  = ws_in + V_OFF;
    const uint4* img4 = (const uint4*)(ws_in + IMGC_OFF);

    // ---- phase 1: MLP for (k0+kk, px) -> LDS ----
    {
        const int kk  = tid >> 6;            // k slot 0..3
        const int lp  = tid & 63;
        const int px1 = strip * 64 + lp;
        const int k1  = k0 + kk;             // always <= 15 (valid frame)

        const float* up = Ub + (size_t)t  * HIDN * HW + px1;
        const float* vp = Vb + (size_t)k1 * HIDN * HW + px1;

        float res0 = b2s2[0], res1 = b2s2[1];
#pragma unroll
        for (int o = 0; o < HIDN; ++o) {
            float h = fmaxf(up[o * HW] + vp[o * HW], 0.0f);   // coalesced
            res0 = fmaf(w2s[o],        h, res0);
            res1 = fmaf(w2s[HIDN + o], h, res1);
        }

        float dx = (cum[(t * 2)     * HW + px1] - cum[(k1 * 2)     * HW + px1]) + res0;
        float dy = (cum[(t * 2 + 1) * HW + px1] - cum[(k1 * 2 + 1) * HW + px1]) + res1;
        dls[kk][lp] = make_float2(dx, dy);
    }
    __syncthreads();

    // ---- phase 2: gathers ----
    const int lane = tid & 63;        // x coord
    const int cg   = tid >> 6;        // channel group (one per wave)
    const int px   = strip * 64 + lane;

    const float lam = expf(decay_log[0]);
    const float bgx = (float)(2 * lane  + 1) * (1.0f / 64.0f) - 1.0f;
    const float bgy = (float)(2 * strip + 1) * (1.0f / 64.0f) - 1.0f;

    int   off[4][4];
    float cwt[4][4];
#pragma unroll
    for (int dk = 0; dk < 4; ++dk) {
        const int k = k0 + dk;
        const float wtd = (k <= t) ? expf(-lam * (float)(t - k)) : 0.0f;
        float2 d = dls[dk][lane];

        float gx = bgx + d.x;
        float gy = bgy + d.y;

        // wrap x: mod(gx+1, 2) - 1 (floor-mod)
        float xp = gx + 1.0f;
        xp = xp - floorf(xp * 0.5f) * 2.0f;
        float gxw = xp - 1.0f;

        float ix = ((gxw + 1.0f) * 64.0f - 1.0f) * 0.5f;
        float iy = ((gy  + 1.0f) * 64.0f - 1.0f) * 0.5f;

        float ix0f = floorf(ix), iy0f = floorf(iy);
        float fx1 = ix - ix0f, fy1 = iy - iy0f;
        float fx0 = 1.0f - fx1, fy0 = 1.0f - fy1;
        int ix0 = (int)ix0f, iy0 = (int)iy0f;
        int ix1 = ix0 + 1,   iy1 = iy0 + 1;

        int xi[4] = {ix0, ix1, ix0, ix1};
        int yi[4] = {iy0, iy0, iy1, iy1};
        float wwv[4] = {fx0 * fy0, fx1 * fy0, fx0 * fy1, fx1 * fy1};
#pragma unroll
        for (int j = 0; j < 4; ++j) {
            bool valid = (xi[j] >= 0) & (xi[j] < WW) & (yi[j] >= 0) & (yi[j] < HH);
            int xc = min(max(xi[j], 0), WW - 1);
            int yc = min(max(yi[j], 0), HH - 1);
            off[dk][j] = yc * WW + xc;
            cwt[dk][j] = valid ? wwv[j] * wtd : 0.0f;
        }
    }

    // 16 independent dwordx4 gathers (frame k0+dk always a valid frame)
    uint4 q[4][4];
#pragma unroll
    for (int dk = 0; dk < 4; ++dk) {
        const size_t pb = (size_t)((k0 + dk) * 4 + cg) * HW;
#pragma unroll
        for (int j = 0; j < 4; ++j)
            q[dk][j] = img4[pb + off[dk][j]];
    }

    float acc[8];
#pragma unroll
    for (int j = 0; j < 8; ++j) acc[j] = 0.0f;

#pragma unroll
    for (int dk = 0; dk < 4; ++dk) {
#pragma unroll
        for (int j = 0; j < 4; ++j) {
            const float wj = cwt[dk][j];
            const uint4 v = q[dk][j];
            acc[0] = fmaf(wj, bflo(v.x), acc[0]);
            acc[1] = fmaf(wj, bfhi(v.x), acc[1]);
            acc[2] = fmaf(wj, bflo(v.y), acc[2]);
            acc[3] = fmaf(wj, bfhi(v.y), acc[3]);
            acc[4] = fmaf(wj, bflo(v.z), acc[4]);
            acc[5] = fmaf(wj, bfhi(v.z), acc[5]);
            acc[6] = fmaf(wj, bflo(v.w), acc[6]);
            acc[7] = fmaf(wj, bfhi(v.w), acc[7]);
        }
    }

    // store partial slice A[cid][cg*8+j][px] (coalesced per wave)
    float* Ap = ws_out + A_OFF + ((size_t)cid * CC + cg * 8) * HW + px;
#pragma unroll
    for (int j = 0; j < 8; ++j) Ap[j * HW] = acc[j];
}

// ---------------- reduce over k-chunks (pure streaming) ----------------
__global__ __launch_bounds__(256) void reduce_kernel(const float* __restrict__ ws,
                                                     float* __restrict__ out) {
    const int gid = blockIdx.x * 256 + threadIdx.x;  // 0..524287
    const int t   = gid >> 15;                        // 32768 float4 per t
    const int c   = (gid >> 10) & 31;
    const int px4 = gid & 1023;

    const float4* A4 = (const float4*)(ws + A_OFF);
    const int n = 1 + (t >= 4) + (t >= 8) + (t >= 12);

    float4 s = make_float4(0.0f, 0.0f, 0.0f, 0.0f);
    for (int kc = 0; kc < n; ++kc) {
        int cid = SEG[kc] + (t - TMIN[kc]);
        float4 a = A4[((size_t)cid * CC + c) * (HW / 4) + px4];
        s.x += a.x; s.y += a.y; s.z += a.z; s.w += a.w;
    }
    ((float4*)out)[gid] = s;
}

extern "C" void kernel_launch(void* const* d_in, const int* in_sizes, int n_in,
                              void* d_out, int out_size, void* d_ws, size_t ws_size,
                              hipStream_t stream) {
    const float* flows     = (const float*)d_in[0];
    const float* images    = (const float*)d_in[1];
    const float* decay_log = (const float*)d_in[2];
    const float* w1        = (const float*)d_in[3];
    const float* b1        = (const float*)d_in[4];
    const float* w2        = (const float*)d_in[5];
    const float* b2        = (const float*)d_in[6];
    float* out = (float*)d_out;
    float* ws  = (float*)d_ws;

    cumsum_kernel<<<dim3(2 * HW / 256), dim3(256), 0, stream>>>(flows, ws + CUM_OFF);

    prep_kernel<<<dim3(HW / 256, LL), dim3(256), 0, stream>>>(images, w1, b1, ws);

    sample_kernel<<<dim3(8 * 320), dim3(256), 0, stream>>>(ws, ws, w2, b2, decay_log);

    reduce_kernel<<<dim3(2048), dim3(256), 0, stream>>>(ws, out);
}